// Round 1
// baseline (233.548 us; speedup 1.0000x reference)
//
#include <hip/hip_runtime.h>

constexpr int BSNH = 32;
constexpr int NK   = 256;
constexpr int DK   = 64;

__device__ __forceinline__ float4 shfl_down4(float4 v, int off) {
    float4 r;
    r.x = __shfl_down(v.x, off, 64);
    r.y = __shfl_down(v.y, off, 64);
    r.z = __shfl_down(v.z, off, 64);
    r.w = __shfl_down(v.w, off, 64);
    return r;
}

__device__ __forceinline__ void add4(float4& a, const float4 b) {
    a.x += b.x; a.y += b.y; a.z += b.z; a.w += b.w;
}

__global__ __launch_bounds__(256) void sdpa_fused_kernel(
    const float* __restrict__ Q, const float* __restrict__ K,
    const float* __restrict__ V, const float* __restrict__ SA,
    const float* __restrict__ SV, const int* __restrict__ MASK,
    float* __restrict__ OUT,     // (32,256,128)
    float* __restrict__ ATTN)    // (32,256,256)
{
    const int bq   = blockIdx.x;      // b*256 + qi, 0..8191
    const int b    = bq >> 8;
    const int tid  = threadIdx.x;     // 0..255
    const int lane = tid & 63;
    const int wave = tid >> 6;

    __shared__ float  qs[DK];
    __shared__ float  attn_s[NK];
    __shared__ float  redmax[4];
    __shared__ float  redsum[4];
    __shared__ float4 red4[4][16];

    // ---- load Q row into LDS ----
    if (tid < DK) qs[tid] = Q[(size_t)bq * DK + tid];
    __syncthreads();

    // ---- scores: thread tid == key index k ----
    const float4* krow = reinterpret_cast<const float4*>(K + ((size_t)b * NK + tid) * DK);
    float s = 0.f;
    #pragma unroll
    for (int i = 0; i < DK / 4; ++i) {
        float4 kv = krow[i];
        s = fmaf(qs[4*i+0], kv.x, s);
        s = fmaf(qs[4*i+1], kv.y, s);
        s = fmaf(qs[4*i+2], kv.z, s);
        s = fmaf(qs[4*i+3], kv.w, s);
    }
    s *= 0.125f;   // 1/sqrt(64)
    if (MASK[(size_t)bq * NK + tid] == 0) s = -1e9f;

    // ---- block max (256) ----
    float mx = s;
    #pragma unroll
    for (int off = 32; off >= 1; off >>= 1)
        mx = fmaxf(mx, __shfl_down(mx, off, 64));
    if (lane == 0) redmax[wave] = mx;
    __syncthreads();
    mx = fmaxf(fmaxf(redmax[0], redmax[1]), fmaxf(redmax[2], redmax[3]));

    // ---- exp + block sum ----
    const float e = __expf(s - mx);
    float sm = e;
    #pragma unroll
    for (int off = 32; off >= 1; off >>= 1)
        sm += __shfl_down(sm, off, 64);
    if (lane == 0) redsum[wave] = sm;
    __syncthreads();
    const float denom = redsum[0] + redsum[1] + redsum[2] + redsum[3];
    const float a = e / denom;

    attn_s[tid] = a;
    ATTN[(size_t)bq * NK + tid] = a;   // coalesced 1KB row
    __syncthreads();

    // ---- common (d4, kt) mapping: d4 = float4 column, kt = k-slice ----
    const int d4 = tid & 15;   // covers d = 4*d4 .. 4*d4+3
    const int kt = tid >> 4;   // 0..15

    // ---- v_val = sum_k attn[k] * V[b,k,:] ----
    {
        const float4* v4 = reinterpret_cast<const float4*>(V + (size_t)b * NK * DK);
        float4 acc = make_float4(0.f, 0.f, 0.f, 0.f);
        #pragma unroll
        for (int kk = 0; kk < 16; ++kk) {
            const int kidx = kt + kk * 16;
            const float4 vv = v4[kidx * 16 + d4];
            const float  w  = attn_s[kidx];
            acc.x = fmaf(w, vv.x, acc.x);
            acc.y = fmaf(w, vv.y, acc.y);
            acc.z = fmaf(w, vv.z, acc.z);
            acc.w = fmaf(w, vv.w, acc.w);
        }
        add4(acc, shfl_down4(acc, 32));
        add4(acc, shfl_down4(acc, 16));
        if (lane < 16) red4[wave][lane] = acc;
        __syncthreads();
        if (tid < 16) {
            float4 r = red4[0][tid];
            add4(r, red4[1][tid]);
            add4(r, red4[2][tid]);
            add4(r, red4[3][tid]);
            reinterpret_cast<float4*>(OUT)[(size_t)bq * 32 + tid] = r;
        }
        __syncthreads();
    }

    // ---- s_val = (1/256) * sum_k sa[b,q,k,:] * sv[b,q,k,:]  (the HBM stream) ----
    {
        const float4* sa4 = reinterpret_cast<const float4*>(SA + (size_t)bq * NK * DK);
        const float4* sv4 = reinterpret_cast<const float4*>(SV + (size_t)bq * NK * DK);
        float4 acc = make_float4(0.f, 0.f, 0.f, 0.f);
        #pragma unroll 4
        for (int kk = 0; kk < 16; ++kk) {
            const int kidx = kt + kk * 16;
            const float4 av = sa4[kidx * 16 + d4];
            const float4 bv = sv4[kidx * 16 + d4];
            acc.x = fmaf(av.x, bv.x, acc.x);
            acc.y = fmaf(av.y, bv.y, acc.y);
            acc.z = fmaf(av.z, bv.z, acc.z);
            acc.w = fmaf(av.w, bv.w, acc.w);
        }
        add4(acc, shfl_down4(acc, 32));
        add4(acc, shfl_down4(acc, 16));
        if (lane < 16) red4[wave][lane] = acc;
        __syncthreads();
        if (tid < 16) {
            float4 r = red4[0][tid];
            add4(r, red4[1][tid]);
            add4(r, red4[2][tid]);
            add4(r, red4[3][tid]);
            const float scale = 1.f / 256.f;
            r.x *= scale; r.y *= scale; r.z *= scale; r.w *= scale;
            reinterpret_cast<float4*>(OUT)[(size_t)bq * 32 + 16 + tid] = r;
        }
    }
}

extern "C" void kernel_launch(void* const* d_in, const int* in_sizes, int n_in,
                              void* d_out, int out_size, void* d_ws, size_t ws_size,
                              hipStream_t stream) {
    const float* Q    = (const float*)d_in[0];
    const float* K    = (const float*)d_in[1];
    const float* V    = (const float*)d_in[2];
    const float* SA   = (const float*)d_in[3];
    const float* SV   = (const float*)d_in[4];
    const int*   MASK = (const int*)d_in[5];

    float* OUT  = (float*)d_out;                               // 32*256*128 floats
    float* ATTN = OUT + (size_t)BSNH * NK * (2 * DK);          // 32*256*256 floats

    sdpa_fused_kernel<<<dim3(BSNH * NK), dim3(256), 0, stream>>>(
        Q, K, V, SA, SV, MASK, OUT, ATTN);
}

// Round 3
// 185.518 us; speedup vs baseline: 1.2589x; 1.2589x over previous
//
#include <hip/hip_runtime.h>

constexpr int BSNH = 32;
constexpr int NK   = 256;
constexpr int DK   = 64;
constexpr int ROWS = 4;                 // q-rows per block
constexpr int RS4  = NK * (DK / 4);     // float4 stride of one (q) row-block in sa/sv = 4096

typedef float f32x4 __attribute__((ext_vector_type(4)));

__device__ __forceinline__ float4 shfl_down4(float4 v, int off) {
    float4 r;
    r.x = __shfl_down(v.x, off, 64);
    r.y = __shfl_down(v.y, off, 64);
    r.z = __shfl_down(v.z, off, 64);
    r.w = __shfl_down(v.w, off, 64);
    return r;
}

__device__ __forceinline__ void add4(float4& a, const float4 b) {
    a.x += b.x; a.y += b.y; a.z += b.z; a.w += b.w;
}

__global__ __launch_bounds__(256) void sdpa_fused4_kernel(
    const float* __restrict__ Q, const float* __restrict__ K,
    const float* __restrict__ V, const float* __restrict__ SA,
    const float* __restrict__ SV, const int* __restrict__ MASK,
    float* __restrict__ OUT,     // (32,256,128)
    float* __restrict__ ATTN)    // (32,256,256)
{
    const int blk  = blockIdx.x;          // 0..2047
    const int b    = blk >> 6;            // batch-head
    const int q0   = (blk & 63) * ROWS;   // first q row of this tile
    const int tid  = threadIdx.x;
    const int lane = tid & 63;
    const int wave = tid >> 6;

    __shared__ float  qs[ROWS][DK];            // 1 KB
    __shared__ float  attn_s[ROWS][NK];        // 4 KB (scores, then attention)
    __shared__ float4 red4[4][ROWS][16];       // 4 KB

    // ---- load Q tile (4 rows x 64 = 256 floats, one per thread) ----
    qs[tid >> 6][tid & 63] = Q[((size_t)(b * NK + q0)) * DK + tid];
    __syncthreads();

    // ---- scores: thread tid == key index k; 4 dots per thread ----
    {
        const float4* krow = reinterpret_cast<const float4*>(K + ((size_t)b * NK + tid) * DK);
        float sc0 = 0.f, sc1 = 0.f, sc2 = 0.f, sc3 = 0.f;
        #pragma unroll
        for (int i = 0; i < DK / 4; ++i) {
            const float4 kv = krow[i];
            sc0 = fmaf(qs[0][4*i+0], kv.x, sc0); sc0 = fmaf(qs[0][4*i+1], kv.y, sc0);
            sc0 = fmaf(qs[0][4*i+2], kv.z, sc0); sc0 = fmaf(qs[0][4*i+3], kv.w, sc0);
            sc1 = fmaf(qs[1][4*i+0], kv.x, sc1); sc1 = fmaf(qs[1][4*i+1], kv.y, sc1);
            sc1 = fmaf(qs[1][4*i+2], kv.z, sc1); sc1 = fmaf(qs[1][4*i+3], kv.w, sc1);
            sc2 = fmaf(qs[2][4*i+0], kv.x, sc2); sc2 = fmaf(qs[2][4*i+1], kv.y, sc2);
            sc2 = fmaf(qs[2][4*i+2], kv.z, sc2); sc2 = fmaf(qs[2][4*i+3], kv.w, sc2);
            sc3 = fmaf(qs[3][4*i+0], kv.x, sc3); sc3 = fmaf(qs[3][4*i+1], kv.y, sc3);
            sc3 = fmaf(qs[3][4*i+2], kv.z, sc3); sc3 = fmaf(qs[3][4*i+3], kv.w, sc3);
        }
        const int* mrow = MASK + ((size_t)(b * NK + q0)) * NK + tid;
        attn_s[0][tid] = (mrow[0 * NK] == 0) ? -1e9f : sc0 * 0.125f;
        attn_s[1][tid] = (mrow[1 * NK] == 0) ? -1e9f : sc1 * 0.125f;
        attn_s[2][tid] = (mrow[2 * NK] == 0) ? -1e9f : sc2 * 0.125f;
        attn_s[3][tid] = (mrow[3 * NK] == 0) ? -1e9f : sc3 * 0.125f;
    }
    __syncthreads();

    // ---- softmax: wave w owns row w; lane handles 4 columns ----
    {
        const int r = wave;
        float v0 = attn_s[r][lane];
        float v1 = attn_s[r][lane + 64];
        float v2 = attn_s[r][lane + 128];
        float v3 = attn_s[r][lane + 192];
        float m = fmaxf(fmaxf(v0, v1), fmaxf(v2, v3));
        #pragma unroll
        for (int off = 32; off >= 1; off >>= 1)
            m = fmaxf(m, __shfl_xor(m, off, 64));
        const float e0 = __expf(v0 - m), e1 = __expf(v1 - m),
                    e2 = __expf(v2 - m), e3 = __expf(v3 - m);
        float s = e0 + e1 + e2 + e3;
        #pragma unroll
        for (int off = 32; off >= 1; off >>= 1)
            s += __shfl_xor(s, off, 64);
        const float inv = 1.0f / s;
        const float a0 = e0 * inv, a1 = e1 * inv, a2 = e2 * inv, a3 = e3 * inv;
        attn_s[r][lane]       = a0;
        attn_s[r][lane + 64]  = a1;
        attn_s[r][lane + 128] = a2;
        attn_s[r][lane + 192] = a3;
        float* arow = ATTN + ((size_t)(b * NK + q0 + r)) * NK;
        arow[lane]       = a0;
        arow[lane + 64]  = a1;
        arow[lane + 128] = a2;
        arow[lane + 192] = a3;
    }
    __syncthreads();

    const int d4 = tid & 15;   // float4 column
    const int kt = tid >> 4;   // k-slice 0..15

    // ---- v_val: one V load feeds 4 row-accumulators ----
    {
        const float4* v4 = reinterpret_cast<const float4*>(V + (size_t)b * NK * DK);
        float4 acc[ROWS];
        #pragma unroll
        for (int r = 0; r < ROWS; ++r) acc[r] = make_float4(0.f, 0.f, 0.f, 0.f);
        #pragma unroll 4
        for (int kk = 0; kk < 16; ++kk) {
            const int kidx = kt + kk * 16;
            const float4 vv = v4[kidx * 16 + d4];
            #pragma unroll
            for (int r = 0; r < ROWS; ++r) {
                const float w = attn_s[r][kidx];
                acc[r].x = fmaf(w, vv.x, acc[r].x);
                acc[r].y = fmaf(w, vv.y, acc[r].y);
                acc[r].z = fmaf(w, vv.z, acc[r].z);
                acc[r].w = fmaf(w, vv.w, acc[r].w);
            }
        }
        #pragma unroll
        for (int r = 0; r < ROWS; ++r) {
            add4(acc[r], shfl_down4(acc[r], 32));
            add4(acc[r], shfl_down4(acc[r], 16));
        }
        if (lane < 16) {
            #pragma unroll
            for (int r = 0; r < ROWS; ++r) red4[wave][r][lane] = acc[r];
        }
        __syncthreads();
        if (tid < 64) {
            const int r = tid >> 4, c = tid & 15;
            float4 res = red4[0][r][c];
            add4(res, red4[1][r][c]);
            add4(res, red4[2][r][c]);
            add4(res, red4[3][r][c]);
            reinterpret_cast<float4*>(OUT)[(size_t)(b * NK + q0 + r) * 32 + c] = res;
        }
        __syncthreads();
    }

    // ---- s_val: the 1 GB sa*sv stream, non-temporal, 4 rows per block ----
    {
        const f32x4* sa4 = reinterpret_cast<const f32x4*>(SA) + (size_t)(b * NK + q0) * (DK / 4) * NK;
        const f32x4* sv4 = reinterpret_cast<const f32x4*>(SV) + (size_t)(b * NK + q0) * (DK / 4) * NK;
        f32x4 acc[ROWS];
        #pragma unroll
        for (int r = 0; r < ROWS; ++r) acc[r] = (f32x4)(0.f);
        #pragma unroll 2
        for (int kk = 0; kk < 16; ++kk) {
            const size_t o = (size_t)(kt + kk * 16) * 16 + d4;
            f32x4 av[ROWS], bv[ROWS];
            #pragma unroll
            for (int r = 0; r < ROWS; ++r) {
                av[r] = __builtin_nontemporal_load(&sa4[(size_t)r * RS4 + o]);
                bv[r] = __builtin_nontemporal_load(&sv4[(size_t)r * RS4 + o]);
            }
            #pragma unroll
            for (int r = 0; r < ROWS; ++r)
                acc[r] += av[r] * bv[r];
        }
        float4 accf[ROWS];
        #pragma unroll
        for (int r = 0; r < ROWS; ++r) {
            accf[r] = make_float4(acc[r].x, acc[r].y, acc[r].z, acc[r].w);
            add4(accf[r], shfl_down4(accf[r], 32));
            add4(accf[r], shfl_down4(accf[r], 16));
        }
        if (lane < 16) {
            #pragma unroll
            for (int r = 0; r < ROWS; ++r) red4[wave][r][lane] = accf[r];
        }
        __syncthreads();
        if (tid < 64) {
            const int r = tid >> 4, c = tid & 15;
            float4 res = red4[0][r][c];
            add4(res, red4[1][r][c]);
            add4(res, red4[2][r][c]);
            add4(res, red4[3][r][c]);
            const float scale = 1.f / 256.f;
            res.x *= scale; res.y *= scale; res.z *= scale; res.w *= scale;
            reinterpret_cast<float4*>(OUT)[(size_t)(b * NK + q0 + r) * 32 + 16 + c] = res;
        }
    }
}

extern "C" void kernel_launch(void* const* d_in, const int* in_sizes, int n_in,
                              void* d_out, int out_size, void* d_ws, size_t ws_size,
                              hipStream_t stream) {
    const float* Q    = (const float*)d_in[0];
    const float* K    = (const float*)d_in[1];
    const float* V    = (const float*)d_in[2];
    const float* SA   = (const float*)d_in[3];
    const float* SV   = (const float*)d_in[4];
    const int*   MASK = (const int*)d_in[5];

    float* OUT  = (float*)d_out;                        // 32*256*128 floats
    float* ATTN = OUT + (size_t)BSNH * NK * (2 * DK);   // 32*256*256 floats

    sdpa_fused4_kernel<<<dim3(BSNH * NK / ROWS), dim3(256), 0, stream>>>(
        Q, K, V, SA, SV, MASK, OUT, ATTN);
}